// Round 5
// baseline (446.424 us; speedup 1.0000x reference)
//
#include <hip/hip_runtime.h>

// GiGCNConv: out[d] = b + (1/deg[d]) * ( h[d] + sum_{e:(s->d)} ew[e]*h[s] )
//   h = x @ W,  deg[d] = 1 + sum_{e:dst==d} ew[e]
//
// Round-5 pipeline (XCD-partitioned exact counting sort):
//   1. count8:  per-node histogram into 8 PRIVATE copies (g = blockIdx&7 ~ XCD
//               under round-robin dispatch) -> no cross-XCD atomic line sharing
//   2. scan1/2/3: exact exclusive scan over nodes -> node_off, cursor
//               (scan1 sums the 8 copies, also emits cnt totals)
//   3. xscatter: 8 groups; group g NT-reads ALL dst but scatters only edges
//               with dst in its contiguous N/8 range. Group g's cursors (50KB)
//               and pair region (3.2MB) stay in ONE XCD's L2 -> write lines
//               fill before eviction (round-4 bscatter wrote 186MB for 25.6MB
//               of data because all 8 XCDs thrashed the full region).
//   4. gemm16:  h = x @ W stored BF16 (halves gather bytes)
//   5. accum:   wave-per-node register accumulation, unroll x8, NT pair loads,
//               NT out stores. No sort fixup needed (scatter is exact).
//
// Inputs: x f32[N*64], edge_index i32[2*E], edge_weight f32[E],
//         W f32[64*64], b f32[64].  Output f32[N*64].

#define D 64
#define SCAN_BLK 256

static __device__ __forceinline__ unsigned short f2bf(float f) {
    unsigned u = __float_as_uint(f);
    u += 0x7FFFu + ((u >> 16) & 1u);   // round-to-nearest-even
    return (unsigned short)(u >> 16);
}
static __device__ __forceinline__ float bf2f(unsigned short s) {
    return __uint_as_float(((unsigned)s) << 16);
}

// ---------------- 1. per-node count, 8 private copies ----------------

__global__ __launch_bounds__(256) void count8_kernel(const int* __restrict__ dst,
                                                     int* __restrict__ cnt8,
                                                     int E, int Npad) {
    int g = blockIdx.x & 7;
    int* my = cnt8 + (size_t)g * Npad;
    int t = blockIdx.x * 256 + threadIdx.x;
    int stride = gridDim.x * 256;
    for (int e = t; e < E; e += stride) {
        int d = __builtin_nontemporal_load(dst + e);
        atomicAdd(&my[d], 1);
    }
}

// ---------------- 2. scan ----------------

// sums the 8 count copies -> cnt[i]; per-block inclusive scan -> part, bsum
__global__ __launch_bounds__(SCAN_BLK) void scan1_kernel(const int* __restrict__ cnt8,
                                                         int* __restrict__ cnt,
                                                         int* __restrict__ part,
                                                         int* __restrict__ bsum,
                                                         int N, int Npad) {
    __shared__ int s[SCAN_BLK];
    int i = blockIdx.x * SCAN_BLK + threadIdx.x;
    int v = 0;
    if (i < N) {
#pragma unroll
        for (int g = 0; g < 8; ++g) v += cnt8[(size_t)g * Npad + i];
        cnt[i] = v;
    }
    s[threadIdx.x] = v;
    __syncthreads();
    for (int o = 1; o < SCAN_BLK; o <<= 1) {
        int t = (threadIdx.x >= (unsigned)o) ? s[threadIdx.x - o] : 0;
        __syncthreads();
        s[threadIdx.x] += t;
        __syncthreads();
    }
    if (i < N) part[i] = s[threadIdx.x];
    if (threadIdx.x == SCAN_BLK - 1) bsum[blockIdx.x] = s[threadIdx.x];
}

// single-block exclusive scan of bsum (G elements), in place
__global__ __launch_bounds__(SCAN_BLK) void scan2_kernel(int* __restrict__ bsum, int G) {
    __shared__ int s[SCAN_BLK];
    __shared__ int carry;
    if (threadIdx.x == 0) carry = 0;
    __syncthreads();
    for (int base = 0; base < G; base += SCAN_BLK) {
        int i = base + threadIdx.x;
        int v = (i < G) ? bsum[i] : 0;
        s[threadIdx.x] = v;
        __syncthreads();
        for (int o = 1; o < SCAN_BLK; o <<= 1) {
            int t = (threadIdx.x >= (unsigned)o) ? s[threadIdx.x - o] : 0;
            __syncthreads();
            s[threadIdx.x] += t;
            __syncthreads();
        }
        int incl = s[threadIdx.x];
        if (i < G) bsum[i] = carry + incl - v;  // exclusive
        __syncthreads();
        if (threadIdx.x == SCAN_BLK - 1) carry += incl;
        __syncthreads();
    }
}

// off[i] = exclusive scan; cursor[i] = off[i]
__global__ __launch_bounds__(SCAN_BLK) void scan3_kernel(const int* __restrict__ cnt,
                                                         int* __restrict__ part_off,
                                                         int* __restrict__ cursor,
                                                         const int* __restrict__ bsum, int N) {
    int i = blockIdx.x * SCAN_BLK + threadIdx.x;
    if (i < N) {
        int ex = part_off[i] - cnt[i] + bsum[blockIdx.x];
        part_off[i] = ex;
        cursor[i] = ex;
    }
}

// ---------------- 3. XCD-partitioned exact scatter ----------------

__global__ __launch_bounds__(256) void xscatter_kernel(const int* __restrict__ src,
                                                       const int* __restrict__ dst,
                                                       const float* __restrict__ ew,
                                                       int* __restrict__ cursor,
                                                       int2* __restrict__ pairs,
                                                       int E, unsigned q) {
    unsigned g = blockIdx.x & 7;
    int rank = blockIdx.x >> 3;
    int nrank = gridDim.x >> 3;
    int t = rank * 256 + threadIdx.x;
    int stride = nrank * 256;
    for (int e = t; e < E; e += stride) {
        int d = __builtin_nontemporal_load(dst + e);
        if ((unsigned)d / q == g) {
            int s = __builtin_nontemporal_load(src + e);
            float w = __builtin_nontemporal_load(ew + e);
            int pos = atomicAdd(&cursor[d], 1);
            pairs[pos] = make_int2(s, __float_as_int(w));
        }
    }
}

// ---------------- 4. h = x @ W -> bf16 ----------------

__global__ __launch_bounds__(256) void gemm16_kernel(const float* __restrict__ x,
                                                     const float* __restrict__ W,
                                                     unsigned short* __restrict__ hbf, int N) {
    __shared__ float Ws[D * D];
    __shared__ float xs[16][D];
    int tid = threadIdx.x;
    int j = tid & 63;
    int q = tid >> 6;
    int base = blockIdx.x * 16;
    for (int i = tid; i < D * D; i += 256) Ws[i] = W[i];
    for (int rr = q; rr < 16; rr += 4) {
        int r = base + rr;
        if (r < N) xs[rr][j] = x[(size_t)r * D + j];
    }
    __syncthreads();
    for (int rr = q; rr < 16; rr += 4) {
        int r = base + rr;
        if (r < N) {
            float sum = 0.0f;
#pragma unroll
            for (int k = 0; k < D; ++k) sum = fmaf(xs[rr][k], Ws[k * D + j], sum);
            hbf[(size_t)r * D + j] = f2bf(sum);
        }
    }
}

// ---------------- 5. accumulate: wave-per-node ----------------

__global__ __launch_bounds__(256) void accum_kernel(const int2* __restrict__ pairs,
                                                    const int* __restrict__ node_off,
                                                    const int* __restrict__ cnt,
                                                    const unsigned short* __restrict__ hbf,
                                                    const float* __restrict__ bias,
                                                    float* __restrict__ out, int N) {
    int t = blockIdx.x * 256 + threadIdx.x;
    int n = t >> 6;
    int j = t & 63;
    if (n >= N) return;
    float acc = bf2f(hbf[(size_t)n * D + j]);   // self loop, weight 1
    float degs = 1.0f;
    int base = node_off[n];
    int c = cnt[n];
    const long long* pp = (const long long*)(pairs + base);
    int i = 0;
    for (; i + 7 < c; i += 8) {
        long long q0 = __builtin_nontemporal_load(pp + i + 0);
        long long q1 = __builtin_nontemporal_load(pp + i + 1);
        long long q2 = __builtin_nontemporal_load(pp + i + 2);
        long long q3 = __builtin_nontemporal_load(pp + i + 3);
        long long q4 = __builtin_nontemporal_load(pp + i + 4);
        long long q5 = __builtin_nontemporal_load(pp + i + 5);
        long long q6 = __builtin_nontemporal_load(pp + i + 6);
        long long q7 = __builtin_nontemporal_load(pp + i + 7);
        float h0 = bf2f(hbf[(size_t)(int)q0 * D + j]);
        float h1 = bf2f(hbf[(size_t)(int)q1 * D + j]);
        float h2 = bf2f(hbf[(size_t)(int)q2 * D + j]);
        float h3 = bf2f(hbf[(size_t)(int)q3 * D + j]);
        float h4 = bf2f(hbf[(size_t)(int)q4 * D + j]);
        float h5 = bf2f(hbf[(size_t)(int)q5 * D + j]);
        float h6 = bf2f(hbf[(size_t)(int)q6 * D + j]);
        float h7 = bf2f(hbf[(size_t)(int)q7 * D + j]);
        float w0 = __int_as_float((int)(q0 >> 32));
        float w1 = __int_as_float((int)(q1 >> 32));
        float w2 = __int_as_float((int)(q2 >> 32));
        float w3 = __int_as_float((int)(q3 >> 32));
        float w4 = __int_as_float((int)(q4 >> 32));
        float w5 = __int_as_float((int)(q5 >> 32));
        float w6 = __int_as_float((int)(q6 >> 32));
        float w7 = __int_as_float((int)(q7 >> 32));
        degs += ((w0 + w1) + (w2 + w3)) + ((w4 + w5) + (w6 + w7));
        acc = fmaf(w0, h0, acc);
        acc = fmaf(w1, h1, acc);
        acc = fmaf(w2, h2, acc);
        acc = fmaf(w3, h3, acc);
        acc = fmaf(w4, h4, acc);
        acc = fmaf(w5, h5, acc);
        acc = fmaf(w6, h6, acc);
        acc = fmaf(w7, h7, acc);
    }
    for (; i < c; ++i) {
        long long qv = __builtin_nontemporal_load(pp + i);
        float w = __int_as_float((int)(qv >> 32));
        degs += w;
        acc = fmaf(w, bf2f(hbf[(size_t)(int)qv * D + j]), acc);
    }
    float di = (degs > 0.0f) ? (1.0f / degs) : 0.0f;
    __builtin_nontemporal_store(fmaf(di, acc, bias[j]), &out[(size_t)n * D + j]);
}

// ---------------- fallback (round-1 atomic path) ----------------

__global__ __launch_bounds__(256) void deg_kernel(const int* __restrict__ dst,
                                                  const float* __restrict__ ew,
                                                  float* __restrict__ deg, int E) {
    int t = blockIdx.x * 256 + threadIdx.x;
    int stride = gridDim.x * 256;
    for (int e = t; e < E; e += stride) atomicAdd(&deg[dst[e]], ew[e]);
}

__global__ __launch_bounds__(256) void deginv_kernel(float* __restrict__ deg, int N) {
    int t = blockIdx.x * 256 + threadIdx.x;
    int stride = gridDim.x * 256;
    for (int n = t; n < N; n += stride) {
        float tot = deg[n] + 1.0f;
        deg[n] = (tot > 0.0f) ? (1.0f / tot) : 0.0f;
    }
}

__global__ __launch_bounds__(256) void gemm16f_kernel(const float* __restrict__ x,
                                                      const float* __restrict__ W,
                                                      float* __restrict__ h, int N) {
    __shared__ float Ws[D * D];
    __shared__ float xs[16][D];
    int tid = threadIdx.x;
    int j = tid & 63;
    int q = tid >> 6;
    int base = blockIdx.x * 16;
    for (int i = tid; i < D * D; i += 256) Ws[i] = W[i];
    for (int rr = q; rr < 16; rr += 4) {
        int r = base + rr;
        if (r < N) xs[rr][j] = x[(size_t)r * D + j];
    }
    __syncthreads();
    for (int rr = q; rr < 16; rr += 4) {
        int r = base + rr;
        if (r < N) {
            float sum = 0.0f;
#pragma unroll
            for (int k = 0; k < D; ++k) sum = fmaf(xs[rr][k], Ws[k * D + j], sum);
            h[(size_t)r * D + j] = sum;
        }
    }
}

__global__ __launch_bounds__(256) void init_kernel(const float* __restrict__ h,
                                                   const float* __restrict__ deginv,
                                                   const float* __restrict__ b,
                                                   float* __restrict__ out, int N) {
    int t = blockIdx.x * 256 + threadIdx.x;
    int stride = gridDim.x * 256;
    int nq = N * (D / 4);
    const float4* h4 = (const float4*)h;
    const float4* b4 = (const float4*)b;
    float4* o4 = (float4*)out;
    for (int q = t; q < nq; q += stride) {
        int n = q >> 4;
        int c4 = q & 15;
        float4 hv = h4[q];
        float4 bv = b4[c4];
        float di = deginv[n];
        float4 o;
        o.x = bv.x + di * hv.x;
        o.y = bv.y + di * hv.y;
        o.z = bv.z + di * hv.z;
        o.w = bv.w + di * hv.w;
        o4[q] = o;
    }
}

__global__ __launch_bounds__(256) void scatter_kernel(const int* __restrict__ src,
                                                      const int* __restrict__ dst,
                                                      const float* __restrict__ ew,
                                                      const float* __restrict__ deginv,
                                                      const float* __restrict__ h,
                                                      float* __restrict__ out, int E) {
    int t = blockIdx.x * 256 + threadIdx.x;
    int wave = t >> 6;
    int lane = t & 63;
    int nwaves = (gridDim.x * 256) >> 6;
    for (int e = wave; e < E; e += nwaves) {
        int s = src[e];
        int d = dst[e];
        float norm = deginv[d] * ew[e];
        atomicAdd(&out[d * D + lane], norm * h[s * D + lane]);
    }
}

// ---------------- launcher ----------------

extern "C" void kernel_launch(void* const* d_in, const int* in_sizes, int n_in,
                              void* d_out, int out_size, void* d_ws, size_t ws_size,
                              hipStream_t stream) {
    const float* x  = (const float*)d_in[0];
    const int*   ei = (const int*)d_in[1];
    const float* ew = (const float*)d_in[2];
    const float* W  = (const float*)d_in[3];
    const float* b  = (const float*)d_in[4];
    float* out = (float*)d_out;

    int N = in_sizes[0] / D;
    int E = in_sizes[2];
    const int* srcp = ei;
    const int* dstp = ei + E;

    int Npad = (int)(((size_t)N + 63) & ~(size_t)63);
    int G1 = (N + SCAN_BLK - 1) / SCAN_BLK;
    size_t Gpad = ((size_t)G1 + 63) & ~(size_t)63;
    unsigned q = (unsigned)((N + 7) / 8);   // contiguous dst range per group

    // ws layout (ints): cnt8[8*Npad] | cnt[Npad] | off[Npad] | cursor[Npad] | bsum[Gpad]
    // then hbf (N*D ushort, 128B aligned), then pairs (E int2)
    size_t ints_n = (size_t)Npad * 11 + Gpad;
    size_t hbf_off = ((ints_n * 4) + 127) & ~(size_t)127;
    size_t pairs_off = (hbf_off + (size_t)N * D * 2 + 127) & ~(size_t)127;
    size_t need = pairs_off + (size_t)E * 8;

    if (ws_size >= need) {
        int* cnt8   = (int*)d_ws;
        int* cnt    = cnt8 + (size_t)Npad * 8;
        int* off    = cnt + Npad;
        int* cursor = off + Npad;
        int* bsum   = cursor + Npad;
        unsigned short* hbf = (unsigned short*)((char*)d_ws + hbf_off);
        int2* pairs = (int2*)((char*)d_ws + pairs_off);

        hipMemsetAsync(cnt8, 0, (size_t)Npad * 8 * 4, stream);
        count8_kernel<<<2048, 256, 0, stream>>>(dstp, cnt8, E, Npad);
        scan1_kernel<<<G1, SCAN_BLK, 0, stream>>>(cnt8, cnt, off, bsum, N, Npad);
        scan2_kernel<<<1, SCAN_BLK, 0, stream>>>(bsum, G1);
        scan3_kernel<<<G1, SCAN_BLK, 0, stream>>>(cnt, off, cursor, bsum, N);
        xscatter_kernel<<<2048, 256, 0, stream>>>(srcp, dstp, ew, cursor, pairs, E, q);
        gemm16_kernel<<<(N + 15) / 16, 256, 0, stream>>>(x, W, hbf, N);
        accum_kernel<<<(N + 3) / 4, 256, 0, stream>>>(pairs, off, cnt, hbf, b, out, N);
    } else {
        // fallback: atomic scatter path
        float* deg = (float*)d_ws;
        float* h = deg + Npad;
        hipMemsetAsync(deg, 0, (size_t)N * sizeof(float), stream);
        deg_kernel<<<2048, 256, 0, stream>>>(dstp, ew, deg, E);
        deginv_kernel<<<(N + 255) / 256, 256, 0, stream>>>(deg, N);
        gemm16f_kernel<<<(N + 15) / 16, 256, 0, stream>>>(x, W, h, N);
        init_kernel<<<2048, 256, 0, stream>>>(h, deg, b, out, N);
        scatter_kernel<<<2048, 256, 0, stream>>>(srcp, dstp, ew, deg, h, out, E);
    }
}

// Round 6
// 314.754 us; speedup vs baseline: 1.4183x; 1.4183x over previous
//
#include <hip/hip_runtime.h>

// GiGCNConv: out[d] = b + (1/deg[d]) * ( h[d] + sum_{e:(s->d)} ew[e]*h[s] )
//   h = x @ W,  deg[d] = 1 + sum_{e:dst==d} ew[e]
//
// Round-6: two-level LDS-staged partition -> exact per-node CSR -> register accum.
//   Random 8B scatter writes were 163-199MB (6-8x amplification) in rounds 2-5
//   regardless of bucketing/XCD tricks. Fix: batch 2048 edges in LDS, reserve
//   per-bin contiguous ranges with ONE global atomicAdd per bin per batch, and
//   write pairs as multi-line contiguous runs. Line-dense by construction.
//   Level 1: 64 coarse buckets (dst>>11, 2048 nodes)  -> ~336B runs
//   Level 2: 128 sub-buckets/coarse (16 nodes)        -> ~128B runs
//   Then round-4's proven wsort (exact per-node sort in LDS) + accum.
//   hbf (bf16 h) overlays the dead pairs1 region to stay in ws budget.
//
// Inputs: x f32[N*64], edge_index i32[2*E], edge_weight f32[E],
//         W f32[64*64], b f32[64].  Output f32[N*64].

#define D 64
#define SH1 11               // coarse bucket = dst >> 11
#define MAXB1 64             // max coarse buckets (N <= 131072)
#define SUBPB 128            // sub-buckets per coarse bucket (16 nodes each)
#define MAXB2 8192           // max sub-buckets
#define BATCH 2048
#define CAP 1024             // wsort tile capacity (per 16-node bucket)
#define C1S 32               // cursor1 pad stride (ints)
#define C2S 8                // cursor2 pad stride (ints)

static __device__ __forceinline__ unsigned short f2bf(float f) {
    unsigned u = __float_as_uint(f);
    u += 0x7FFFu + ((u >> 16) & 1u);   // round-to-nearest-even
    return (unsigned short)(u >> 16);
}
static __device__ __forceinline__ float bf2f(unsigned short s) {
    return __uint_as_float(((unsigned)s) << 16);
}

// ---------------- 1. sub-bucket histogram (LDS) ----------------

__global__ __launch_bounds__(256) void hist_kernel(const int* __restrict__ dst,
                                                   int* __restrict__ hist, int E, int B2) {
    __shared__ int lh[MAXB2];
    int tid = threadIdx.x;
    for (int i = tid; i < B2; i += 256) lh[i] = 0;
    __syncthreads();
    int t = blockIdx.x * 256 + tid;
    int stride = gridDim.x * 256;
    for (int e = t; e < E; e += stride) {
        int d = __builtin_nontemporal_load(dst + e);
        atomicAdd(&lh[d >> 4], 1);
    }
    __syncthreads();
    for (int i = tid; i < B2; i += 256) {
        int v = lh[i];
        if (v) atomicAdd(&hist[i], v);
    }
}

// ---------------- 2. scan: off2/cur2 (sub) + off1/cur1 (coarse) ----------------

__global__ __launch_bounds__(256) void scan_kernel(const int* __restrict__ hist,
                                                   int* __restrict__ off2,
                                                   int* __restrict__ cur2,
                                                   int* __restrict__ off1,
                                                   int* __restrict__ cur1,
                                                   int B2, int E) {
    __shared__ int s[256];
    __shared__ int carry;
    int tid = threadIdx.x;
    if (tid == 0) carry = 0;
    __syncthreads();
    for (int base = 0; base < B2; base += 256) {
        int i = base + tid;
        int v = (i < B2) ? hist[i] : 0;
        s[tid] = v;
        __syncthreads();
        for (int o = 1; o < 256; o <<= 1) {
            int t = (tid >= o) ? s[tid - o] : 0;
            __syncthreads();
            s[tid] += t;
            __syncthreads();
        }
        int incl = s[tid];
        if (i < B2) {
            int ex = carry + incl - v;
            off2[i] = ex;
            cur2[i * C2S] = ex;
            if ((i & (SUBPB - 1)) == 0) {
                off1[i >> 7] = ex;
                cur1[(i >> 7) * C1S] = ex;
            }
        }
        __syncthreads();
        if (tid == 255) carry += incl;
        __syncthreads();
    }
    if (tid == 0) {
        off2[B2] = E;
        off1[(B2 + SUBPB - 1) >> 7] = E;
    }
}

// ---------------- 3. level-1 staged partition ----------------
// pair1 = { src | (dst & 2047) << 17 , ew }   (src needs <= 17 bits)

__global__ __launch_bounds__(256) void partA_kernel(const int* __restrict__ src,
                                                    const int* __restrict__ dst,
                                                    const float* __restrict__ ew,
                                                    int* __restrict__ cur1,
                                                    int2* __restrict__ pairs1,
                                                    int E, int nb) {
    __shared__ int2 tile[BATCH];
    __shared__ unsigned char binarr[BATCH];
    __shared__ int bcnt[MAXB1];
    __shared__ int bbase[MAXB1];
    __shared__ int brank[MAXB1];
    int tid = threadIdx.x;
    for (int ib = blockIdx.x; ib < nb; ib += gridDim.x) {
        int base = ib * BATCH;
        if (tid < MAXB1) { bcnt[tid] = 0; brank[tid] = 0; }
        __syncthreads();
#pragma unroll
        for (int k = 0; k < BATCH / 256; ++k) {
            int idx = k * 256 + tid;
            int e = base + idx;
            if (e < E) {
                int d = __builtin_nontemporal_load(dst + e);
                int sv = __builtin_nontemporal_load(src + e);
                float w = __builtin_nontemporal_load(ew + e);
                int bin = d >> SH1;
                tile[idx] = make_int2(sv | ((d & ((1 << SH1) - 1)) << 17),
                                      __float_as_int(w));
                binarr[idx] = (unsigned char)bin;
                atomicAdd(&bcnt[bin], 1);
            }
        }
        __syncthreads();
        if (tid < MAXB1 && bcnt[tid] > 0)
            bbase[tid] = atomicAdd(&cur1[tid * C1S], bcnt[tid]);
        __syncthreads();
#pragma unroll
        for (int k = 0; k < BATCH / 256; ++k) {
            int idx = k * 256 + tid;
            int e = base + idx;
            if (e < E) {
                int bin = binarr[idx];
                int r = atomicAdd(&brank[bin], 1);
                pairs1[bbase[bin] + r] = tile[idx];
            }
        }
        __syncthreads();
    }
}

// ---------------- 4. level-2 staged partition ----------------
// pair2 = { src | (dst & 15) << 20 , ew }   (wsort/accum format)

__global__ __launch_bounds__(256) void partB_kernel(const int2* __restrict__ pairs1,
                                                    const int* __restrict__ off1,
                                                    int* __restrict__ cur2,
                                                    int2* __restrict__ pairs2, int B1) {
    __shared__ int2 tile[BATCH];
    __shared__ unsigned char binarr[BATCH];
    __shared__ int bcnt[SUBPB];
    __shared__ int bbase[SUBPB];
    __shared__ int brank[SUBPB];
    int tid = threadIdx.x;
    int c = blockIdx.x >> 4;      // 16 blocks per coarse bucket
    int r = blockIdx.x & 15;
    if (c >= B1) return;
    int e0 = off1[c], e1 = off1[c + 1];
    int cnt = e1 - e0;
    if (cnt <= 0) return;
    int nbc = (cnt + BATCH - 1) / BATCH;
    int curbase = c * SUBPB;
    for (int ib = r; ib < nbc; ib += 16) {
        int bstart = e0 + ib * BATCH;
        int blen = e1 - bstart;
        if (blen > BATCH) blen = BATCH;
        if (tid < SUBPB) { bcnt[tid] = 0; brank[tid] = 0; }
        __syncthreads();
#pragma unroll
        for (int k = 0; k < BATCH / 256; ++k) {
            int idx = k * 256 + tid;
            if (idx < blen) {
                long long v = __builtin_nontemporal_load(
                    (const long long*)(pairs1 + bstart + idx));
                int px = (int)v;
                int bin = (px >> 21) & (SUBPB - 1);
                tile[idx] = make_int2(px, (int)(v >> 32));
                binarr[idx] = (unsigned char)bin;
                atomicAdd(&bcnt[bin], 1);
            }
        }
        __syncthreads();
        if (tid < SUBPB && bcnt[tid] > 0)
            bbase[tid] = atomicAdd(&cur2[(curbase + tid) * C2S], bcnt[tid]);
        __syncthreads();
#pragma unroll
        for (int k = 0; k < BATCH / 256; ++k) {
            int idx = k * 256 + tid;
            if (idx < blen) {
                int2 p = tile[idx];
                int bin = binarr[idx];
                int rk = atomicAdd(&brank[bin], 1);
                int dl = (p.x >> 17) & 15;
                pairs2[bbase[bin] + rk] =
                    make_int2((p.x & 0x1FFFF) | (dl << 20), p.y);
            }
        }
        __syncthreads();
    }
}

// ---------------- 5. wave-per-bucket exact sort (in place) ----------------

__global__ __launch_bounds__(256) void wsort_kernel(const int* __restrict__ off,
                                                    int2* __restrict__ pairs,
                                                    int* __restrict__ node_off,
                                                    int* __restrict__ bad, int B2) {
    __shared__ int2 tile[4][CAP];      // 32 KB
    __shared__ int cnt[4][16];
    __shared__ int excl[4][17];
    __shared__ int cur[4][16];
    int tid = threadIdx.x;
    int lane = tid & 63;
    int w = tid >> 6;
    int b = blockIdx.x * 4 + w;
    bool valid = (b < B2);
    int e0 = valid ? off[b] : 0;
    int e1 = valid ? off[b + 1] : 0;
    int c = e1 - e0;
    bool ok = valid && (c <= CAP);

    if (lane < 16) cnt[w][lane] = 0;
    if (ok) for (int i = lane; i < c; i += 64) tile[w][i] = pairs[e0 + i];
    __syncthreads();
    if (ok) for (int i = lane; i < c; i += 64)
        atomicAdd(&cnt[w][(tile[w][i].x >> 20) & 15], 1);
    __syncthreads();
    if (lane == 0) {
        int run = 0;
        for (int g = 0; g < 16; ++g) { excl[w][g] = ok ? run : 0; run += cnt[w][g]; }
        excl[w][16] = c;
        if (valid && !ok) bad[b] = 1;
    }
    __syncthreads();
    if (valid && lane <= 16) node_off[(b << 4) + lane] = e0 + excl[w][lane];
    if (lane < 16) cur[w][lane] = excl[w][lane];
    __syncthreads();
    if (ok) for (int i = lane; i < c; i += 64) {
        int2 p = tile[w][i];
        int dl = (p.x >> 20) & 15;
        int pos = atomicAdd(&cur[w][dl], 1);
        pairs[e0 + pos] = make_int2(p.x & 0xFFFFF, p.y);   // strip dl
    }
}

// ---------------- 6. h = x @ W -> bf16 ----------------

__global__ __launch_bounds__(256) void gemm16_kernel(const float* __restrict__ x,
                                                     const float* __restrict__ W,
                                                     unsigned short* __restrict__ hbf, int N) {
    __shared__ float Ws[D * D];
    __shared__ float xs[16][D];
    int tid = threadIdx.x;
    int j = tid & 63;
    int q = tid >> 6;
    int base = blockIdx.x * 16;
    for (int i = tid; i < D * D; i += 256) Ws[i] = W[i];
    for (int rr = q; rr < 16; rr += 4) {
        int r = base + rr;
        if (r < N) xs[rr][j] = x[(size_t)r * D + j];
    }
    __syncthreads();
    for (int rr = q; rr < 16; rr += 4) {
        int r = base + rr;
        if (r < N) {
            float sum = 0.0f;
#pragma unroll
            for (int k = 0; k < D; ++k) sum = fmaf(xs[rr][k], Ws[k * D + j], sum);
            hbf[(size_t)r * D + j] = f2bf(sum);
        }
    }
}

// ---------------- 7. accumulate: wave-per-node ----------------

__global__ __launch_bounds__(256) void accum_kernel(const int2* __restrict__ pairs,
                                                    const int* __restrict__ node_off,
                                                    const int* __restrict__ off,
                                                    const int* __restrict__ bad,
                                                    const unsigned short* __restrict__ hbf,
                                                    const float* __restrict__ bias,
                                                    float* __restrict__ out, int N) {
    int t = blockIdx.x * 256 + threadIdx.x;
    int n = t >> 6;
    int j = t & 63;
    if (n >= N) return;
    float acc = bf2f(hbf[(size_t)n * D + j]);   // self loop, weight 1
    float degs = 1.0f;
    int b = n >> 4;
    if (!bad[b]) {
        int base = node_off[n];
        int c = node_off[n + 1] - base;
        const long long* pp = (const long long*)(pairs + base);
        int i = 0;
        for (; i + 7 < c; i += 8) {
            long long q0 = __builtin_nontemporal_load(pp + i + 0);
            long long q1 = __builtin_nontemporal_load(pp + i + 1);
            long long q2 = __builtin_nontemporal_load(pp + i + 2);
            long long q3 = __builtin_nontemporal_load(pp + i + 3);
            long long q4 = __builtin_nontemporal_load(pp + i + 4);
            long long q5 = __builtin_nontemporal_load(pp + i + 5);
            long long q6 = __builtin_nontemporal_load(pp + i + 6);
            long long q7 = __builtin_nontemporal_load(pp + i + 7);
            float h0 = bf2f(hbf[(size_t)(int)q0 * D + j]);
            float h1 = bf2f(hbf[(size_t)(int)q1 * D + j]);
            float h2 = bf2f(hbf[(size_t)(int)q2 * D + j]);
            float h3 = bf2f(hbf[(size_t)(int)q3 * D + j]);
            float h4 = bf2f(hbf[(size_t)(int)q4 * D + j]);
            float h5 = bf2f(hbf[(size_t)(int)q5 * D + j]);
            float h6 = bf2f(hbf[(size_t)(int)q6 * D + j]);
            float h7 = bf2f(hbf[(size_t)(int)q7 * D + j]);
            float w0 = __int_as_float((int)(q0 >> 32));
            float w1 = __int_as_float((int)(q1 >> 32));
            float w2 = __int_as_float((int)(q2 >> 32));
            float w3 = __int_as_float((int)(q3 >> 32));
            float w4 = __int_as_float((int)(q4 >> 32));
            float w5 = __int_as_float((int)(q5 >> 32));
            float w6 = __int_as_float((int)(q6 >> 32));
            float w7 = __int_as_float((int)(q7 >> 32));
            degs += ((w0 + w1) + (w2 + w3)) + ((w4 + w5) + (w6 + w7));
            acc = fmaf(w0, h0, acc);
            acc = fmaf(w1, h1, acc);
            acc = fmaf(w2, h2, acc);
            acc = fmaf(w3, h3, acc);
            acc = fmaf(w4, h4, acc);
            acc = fmaf(w5, h5, acc);
            acc = fmaf(w6, h6, acc);
            acc = fmaf(w7, h7, acc);
        }
        for (; i < c; ++i) {
            long long qv = __builtin_nontemporal_load(pp + i);
            float w = __int_as_float((int)(qv >> 32));
            degs += w;
            acc = fmaf(w, bf2f(hbf[(size_t)(int)qv * D + j]), acc);
        }
    } else {
        // oversized bucket: pairs unsorted (dl packed) — filter scan
        int e0 = off[b], e1 = off[b + 1];
        int dl = n & 15;
        for (int e = e0; e < e1; ++e) {
            int2 p = pairs[e];
            if (((p.x >> 20) & 15) == dl) {
                float w = __int_as_float(p.y);
                degs += w;
                acc = fmaf(w, bf2f(hbf[(size_t)(p.x & 0xFFFFF) * D + j]), acc);
            }
        }
    }
    float di = (degs > 0.0f) ? (1.0f / degs) : 0.0f;
    __builtin_nontemporal_store(fmaf(di, acc, bias[j]), &out[(size_t)n * D + j]);
}

// ---------------- fallback (round-1 atomic path) ----------------

__global__ __launch_bounds__(256) void deg_kernel(const int* __restrict__ dst,
                                                  const float* __restrict__ ew,
                                                  float* __restrict__ deg, int E) {
    int t = blockIdx.x * 256 + threadIdx.x;
    int stride = gridDim.x * 256;
    for (int e = t; e < E; e += stride) atomicAdd(&deg[dst[e]], ew[e]);
}

__global__ __launch_bounds__(256) void deginv_kernel(float* __restrict__ deg, int N) {
    int t = blockIdx.x * 256 + threadIdx.x;
    int stride = gridDim.x * 256;
    for (int n = t; n < N; n += stride) {
        float tot = deg[n] + 1.0f;
        deg[n] = (tot > 0.0f) ? (1.0f / tot) : 0.0f;
    }
}

__global__ __launch_bounds__(256) void gemm16f_kernel(const float* __restrict__ x,
                                                      const float* __restrict__ W,
                                                      float* __restrict__ h, int N) {
    __shared__ float Ws[D * D];
    __shared__ float xs[16][D];
    int tid = threadIdx.x;
    int j = tid & 63;
    int q = tid >> 6;
    int base = blockIdx.x * 16;
    for (int i = tid; i < D * D; i += 256) Ws[i] = W[i];
    for (int rr = q; rr < 16; rr += 4) {
        int r = base + rr;
        if (r < N) xs[rr][j] = x[(size_t)r * D + j];
    }
    __syncthreads();
    for (int rr = q; rr < 16; rr += 4) {
        int r = base + rr;
        if (r < N) {
            float sum = 0.0f;
#pragma unroll
            for (int k = 0; k < D; ++k) sum = fmaf(xs[rr][k], Ws[k * D + j], sum);
            h[(size_t)r * D + j] = sum;
        }
    }
}

__global__ __launch_bounds__(256) void init_kernel(const float* __restrict__ h,
                                                   const float* __restrict__ deginv,
                                                   const float* __restrict__ b,
                                                   float* __restrict__ out, int N) {
    int t = blockIdx.x * 256 + threadIdx.x;
    int stride = gridDim.x * 256;
    int nq = N * (D / 4);
    const float4* h4 = (const float4*)h;
    const float4* b4 = (const float4*)b;
    float4* o4 = (float4*)out;
    for (int q = t; q < nq; q += stride) {
        int n = q >> 4;
        int c4 = q & 15;
        float4 hv = h4[q];
        float4 bv = b4[c4];
        float di = deginv[n];
        float4 o;
        o.x = bv.x + di * hv.x;
        o.y = bv.y + di * hv.y;
        o.z = bv.z + di * hv.z;
        o.w = bv.w + di * hv.w;
        o4[q] = o;
    }
}

__global__ __launch_bounds__(256) void scatter_kernel(const int* __restrict__ src,
                                                      const int* __restrict__ dst,
                                                      const float* __restrict__ ew,
                                                      const float* __restrict__ deginv,
                                                      const float* __restrict__ h,
                                                      float* __restrict__ out, int E) {
    int t = blockIdx.x * 256 + threadIdx.x;
    int wave = t >> 6;
    int lane = t & 63;
    int nwaves = (gridDim.x * 256) >> 6;
    for (int e = wave; e < E; e += nwaves) {
        int s = src[e];
        int d = dst[e];
        float norm = deginv[d] * ew[e];
        atomicAdd(&out[d * D + lane], norm * h[s * D + lane]);
    }
}

// ---------------- launcher ----------------

extern "C" void kernel_launch(void* const* d_in, const int* in_sizes, int n_in,
                              void* d_out, int out_size, void* d_ws, size_t ws_size,
                              hipStream_t stream) {
    const float* x  = (const float*)d_in[0];
    const int*   ei = (const int*)d_in[1];
    const float* ew = (const float*)d_in[2];
    const float* W  = (const float*)d_in[3];
    const float* b  = (const float*)d_in[4];
    float* out = (float*)d_out;

    int N = in_sizes[0] / D;
    int E = in_sizes[2];
    const int* srcp = ei;
    const int* dstp = ei + E;

    int B1 = (N + (1 << SH1) - 1) >> SH1;
    int B2 = (N + 15) >> 4;

    // ws layout (ints):
    //   hist[MAXB2] | bad[MAXB2] | off2[MAXB2+64] | cur2[MAXB2*C2S] |
    //   off1[128] | cur1[64*C1S] | node_off[B2*16+64]
    // then region1 = max(pairs1 E*8, hbf N*D*2), region2 = pairs2 E*8
    size_t node_n = (size_t)B2 * 16 + 64;
    size_t ints_n = (size_t)MAXB2 * 2 + (MAXB2 + 64) + (size_t)MAXB2 * C2S
                  + 128 + 64 * C1S + node_n;
    size_t r1_off = ((ints_n * 4) + 255) & ~(size_t)255;
    size_t r1_sz  = (size_t)E * 8;
    size_t hbf_sz = (size_t)N * D * 2;
    if (hbf_sz > r1_sz) r1_sz = hbf_sz;
    size_t r2_off = (r1_off + r1_sz + 255) & ~(size_t)255;
    size_t need = r2_off + (size_t)E * 8;

    if (N <= 131072 && ws_size >= need) {
        int* hist     = (int*)d_ws;
        int* bad      = hist + MAXB2;
        int* off2     = bad + MAXB2;
        int* cur2     = off2 + MAXB2 + 64;
        int* off1     = cur2 + (size_t)MAXB2 * C2S;
        int* cur1     = off1 + 128;
        int* node_off = cur1 + 64 * C1S;
        int2* pairs1  = (int2*)((char*)d_ws + r1_off);
        unsigned short* hbf = (unsigned short*)((char*)d_ws + r1_off);
        int2* pairs2  = (int2*)((char*)d_ws + r2_off);

        hipMemsetAsync(hist, 0, (size_t)MAXB2 * 2 * 4, stream);   // hist + bad
        hist_kernel<<<512, 256, 0, stream>>>(dstp, hist, E, B2);
        scan_kernel<<<1, 256, 0, stream>>>(hist, off2, cur2, off1, cur1, B2, E);
        int nb = (E + BATCH - 1) / BATCH;
        int gA = nb < 1024 ? nb : 1024;
        partA_kernel<<<gA, 256, 0, stream>>>(srcp, dstp, ew, cur1, pairs1, E, nb);
        partB_kernel<<<B1 * 16, 256, 0, stream>>>(pairs1, off1, cur2, pairs2, B1);
        gemm16_kernel<<<(N + 15) / 16, 256, 0, stream>>>(x, W, hbf, N);  // overlays pairs1
        wsort_kernel<<<(B2 + 3) / 4, 256, 0, stream>>>(off2, pairs2, node_off, bad, B2);
        accum_kernel<<<(N + 3) / 4, 256, 0, stream>>>(pairs2, node_off, off2, bad, hbf, b, out, N);
    } else {
        // fallback: atomic scatter path
        size_t Npad = ((size_t)N + 63) & ~(size_t)63;
        float* deg = (float*)d_ws;
        float* h = deg + Npad;
        hipMemsetAsync(deg, 0, (size_t)N * sizeof(float), stream);
        deg_kernel<<<2048, 256, 0, stream>>>(dstp, ew, deg, E);
        deginv_kernel<<<(N + 255) / 256, 256, 0, stream>>>(deg, N);
        gemm16f_kernel<<<(N + 15) / 16, 256, 0, stream>>>(x, W, h, N);
        init_kernel<<<2048, 256, 0, stream>>>(h, deg, b, out, N);
        scatter_kernel<<<2048, 256, 0, stream>>>(srcp, dstp, ew, deg, h, out, E);
    }
}